// Round 22
// baseline (3135.244 us; speedup 1.0000x reference)
//
#include <hip/hip_runtime.h>
#include <stdint.h>

#define TT 512
#define BB 64
#define II 256
#define HS 512          // H
#define HHALF 256       // HH
#define R4H 2048        // 4*H
#define HB_STRIDE 16384 // 256 unit-pair rows x 64 batches per h buffer

typedef __attribute__((ext_vector_type(8))) short short8v;  // 8 bf16 = 4 VGPR
typedef __attribute__((ext_vector_type(4))) float f32x4;

// ---------------------------------------------------------------------------
// Phase 1: PG[t][r][b] = (b_ih[r]+b_hh[r]) + sum_k W_ih[r][k] * X[b][t][k]
// ---------------------------------------------------------------------------
__global__ __launch_bounds__(256) void pregemm(
    const float* __restrict__ X,    // [B][T][I]
    const float* __restrict__ Wih,  // [4H][I]
    const float* __restrict__ bih,
    const float* __restrict__ bhh,
    float* __restrict__ PG)         // [T][4H][B]
{
  __shared__ __align__(16) float Xs[64][68];
  __shared__ __align__(16) float Ws[64][68];
  const int t = blockIdx.x;
  const int rbase = blockIdx.y * 64;
  const int tid = threadIdx.x;
  const int cg = tid & 15;
  const int rg = tid >> 4;

  float acc[4][4] = {};

  for (int k0 = 0; k0 < II; k0 += 64) {
    {
      int b = tid >> 2, kq = tid & 3;
      const float* src = X + ((size_t)b * TT + t) * II + k0 + kq * 16;
      #pragma unroll
      for (int i = 0; i < 16; i += 4) {
        float4 v = *(const float4*)(src + i);
        int kk = kq * 16 + i;
        Xs[kk + 0][b] = v.x; Xs[kk + 1][b] = v.y;
        Xs[kk + 2][b] = v.z; Xs[kk + 3][b] = v.w;
      }
    }
    {
      int r = tid >> 2, kq = tid & 3;
      const float* src = Wih + (size_t)(rbase + r) * II + k0 + kq * 16;
      #pragma unroll
      for (int i = 0; i < 16; i += 4) {
        float4 v = *(const float4*)(src + i);
        int kk = kq * 16 + i;
        Ws[kk + 0][r] = v.x; Ws[kk + 1][r] = v.y;
        Ws[kk + 2][r] = v.z; Ws[kk + 3][r] = v.w;
      }
    }
    __syncthreads();
    #pragma unroll 8
    for (int kk = 0; kk < 64; ++kk) {
      float4 a = *(const float4*)&Ws[kk][rg * 4];
      float4 x = *(const float4*)&Xs[kk][cg * 4];
      float av[4] = {a.x, a.y, a.z, a.w};
      float xv[4] = {x.x, x.y, x.z, x.w};
      #pragma unroll
      for (int i = 0; i < 4; ++i)
        #pragma unroll
        for (int j = 0; j < 4; ++j)
          acc[i][j] = fmaf(av[i], xv[j], acc[i][j]);
    }
    __syncthreads();
  }

  #pragma unroll
  for (int i = 0; i < 4; ++i) {
    int row = rbase + rg * 4 + i;
    float bias = bih[row] + bhh[row];
    float4 o;
    o.x = acc[i][0] + bias; o.y = acc[i][1] + bias;
    o.z = acc[i][2] + bias; o.w = acc[i][3] + bias;
    *(float4*)&PG[((size_t)t * R4H + row) * BB + cg * 4] = o;
  }
}

// ---------------------------------------------------------------------------
__device__ __forceinline__ uint32_t bf16r(float f) {
  uint32_t u = __float_as_uint(f);
  u += 0x7fffu + ((u >> 16) & 1u);
  return u >> 16;
}

// init (unit-major, R9-proven coalesced layout):
// hb[0][uh*64 + b] = pack(bf16(h[2uh]), bf16(h[2uh+1]))
__global__ void init_h(const float* __restrict__ mem, uint32_t* __restrict__ hb)
{
  int idx = blockIdx.x * 256 + threadIdx.x;
  if (idx < HB_STRIDE) {
    int uh = idx >> 6, b = idx & 63;
    float lo = mem[(size_t)b * 1280 + 256 + 2 * uh];
    float hi = mem[(size_t)b * 1280 + 256 + 2 * uh + 1];
    hb[idx] = bf16r(lo) | (bf16r(hi) << 16);
  }
}

// ---------------------------------------------------------------------------
// Cross-XCD h hand-off (proven R6): relaxed agent-scope EXCHANGE stores (RMW
// performed at the IF coherence point; vmcnt(0) ack => globally visible) +
// relaxed agent-scope loads (bypass stale L1/L2). No wbl2/inv sweeps.
// R12-R17 lesson: these MUST be coalesced (unit-major h). R18 proved it:
// WRITE_SIZE 329 -> 100 MB, step 17 -> 4.85 us.
// ---------------------------------------------------------------------------
__device__ __forceinline__ void store_coh_u32(uint32_t* p, uint32_t v) {
  (void)__hip_atomic_exchange(p, v, __ATOMIC_RELAXED, __HIP_MEMORY_SCOPE_AGENT);
}
__device__ __forceinline__ uint32_t load_coh_u32(const uint32_t* p) {
  return __hip_atomic_load(p, __ATOMIC_RELAXED, __HIP_MEMORY_SCOPE_AGENT);
}

// gsum addressing: 2-way-max bank pattern via XOR of bit4 with (row>>2)&1
#define GIDX(row, col) (((row) << 6) + ((col) ^ ((((row) >> 2) & 1) << 4)))

// ---------------------------------------------------------------------------
// Persistent LSTM, MFMA + LDS A-frags + LDS-staged B (R18) + hierarchical
// barrier (R19). grid = 64 WGs x 512 threads; WG g owns units [g*8, g*8+8)
// = 32 gate rows, ALL 64 batches. Wave wu = ONE C-tile: rt=wu>>2, bt=wu&3.
//
// R19: R18's single 64-arrival counter = 64 serialized agent-RMWs on one
// IF cacheline (~2.5-3 us/step, the unexplained stall). Restore the
// R6-PROVEN hierarchical monotonic barrier: 8 first-level counters on
// separate 256B lines (8 arrivals each, pipelined across lines) + 8
// leader-RMWs on a second level + gen publish. Everything else identical
// to R18 (isolate the barrier variable).
// ---------------------------------------------------------------------------
__global__ __launch_bounds__(512) void lstm_persistent(
    const float* __restrict__ mem,   // [B][1280]
    const float* __restrict__ Whh,   // [4H][H] f32
    float* __restrict__ PG,          // [T][4H][B]
    uint32_t* __restrict__ hb,       // [2][256][64] packed bf16x2, unit-major
    float* __restrict__ outmem,      // [B][1280]
    unsigned* __restrict__ bar)      // grpcnt[8]@stride64, cnt2@1024, gen@1088
{
  extern __shared__ uint32_t smem[];
  uint32_t* WA = smem;               // [2048 slots][4] u32 = 32 KB
  uint32_t* HL = smem + 8192;        // [256][66] u32 = 67584 B
  float*  gsum = (float*)(smem + 8192 + 16896);  // [32*64] f32 = 8 KB

  const int g    = blockIdx.x;       // 0..63
  const int tid  = threadIdx.x;
  const int wu   = tid >> 6;         // wave 0..7
  const int lane = tid & 63;
  const int l15  = lane & 15;
  const int lq   = lane >> 4;        // 0..3
  const int bt   = wu & 3;           // batch tile 0..3
  const int rt   = wu >> 2;          // row tile 0..1
  const int u0   = g * 8;

  unsigned* grpcnt = bar + (g >> 3) * 64;   // 8 groups of 8, separate lines
  unsigned* cnt2   = bar + 1024;
  unsigned* gen    = bar + 1088;

  // ---- stage W slice into LDS in A-fragment order (once; R17-proven) ----
  #pragma unroll
  for (int s = 0; s < 4; ++s) {
    int slot = s * 512 + tid;          // 0..2047
    int srt  = slot >> 10;             // 0..1
    int rem  = slot & 1023;
    int sks  = rem >> 6;               // 0..15
    int ln   = rem & 63;
    int sl15 = ln & 15, slq = ln >> 4;
    int lr   = srt * 16 + sl15;        // local gate row
    int grow = (lr >> 3) * HS + u0 + (lr & 7);
    const float* wp = Whh + (size_t)grow * HS + slq * 8 + sks * 32;
    float4 x0 = *(const float4*)(wp);
    float4 x1 = *(const float4*)(wp + 4);
    uint32_t* dst = WA + (size_t)slot * 4;
    dst[0] = bf16r(x0.x) | (bf16r(x0.y) << 16);
    dst[1] = bf16r(x0.z) | (bf16r(x0.w) << 16);
    dst[2] = bf16r(x1.x) | (bf16r(x1.y) << 16);
    dst[3] = bf16r(x1.z) | (bf16r(x1.w) << 16);
  }

  // ---- elementwise state: tid<256, thread = (pair p = tid>>6, batch eb) ----
  const int p = tid >> 6;            // unit-pair 0..3 (valid for tid<256)
  const int eb = lane;
  float c0 = 0.f, c1 = 0.f, m0 = 0.f, m1 = 0.f, h0l = 0.f, h1l = 0.f;
  if (tid < 256) {
    c0 = mem[(size_t)eb * 1280 + 768 + u0 + 2 * p];
    c1 = mem[(size_t)eb * 1280 + 768 + u0 + 2 * p + 1];
    if (u0 < HHALF) {
      m0 = mem[(size_t)eb * 1280 + u0 + 2 * p];
      m1 = mem[(size_t)eb * 1280 + u0 + 2 * p + 1];
    }
  }

  // ---- pg prefetch for t=0 (1 tile x 4 regs per lane) ----
  float pg[4];
  #pragma unroll
  for (int r = 0; r < 4; ++r) {
    int lr = rt * 16 + lq * 4 + r;
    pg[r] = PG[((size_t)0 * R4H + (lr >> 3) * HS + u0 + (lr & 7)) * BB + bt * 16 + l15];
  }

  __syncthreads();  // W staged

  const uint32_t* waBase = WA + ((size_t)(rt * 16) * 64 + lane) * 4;
  const int hlCol = bt * 16 + l15;

  for (int t = 0; t < TT; ++t) {
    // ---- 1. stage h: coalesced sc1 loads -> conflict-free LDS writes ----
    {
      const uint32_t* hcur = hb + (size_t)(t & 1) * HB_STRIDE;
      uint32_t hv[32];
      #pragma unroll
      for (int i = 0; i < 32; ++i) hv[i] = load_coh_u32(hcur + tid + i * 512);
      #pragma unroll
      for (int i = 0; i < 32; ++i) {
        int w = tid + i * 512;                  // kpair = 8i+wu, b = lane
        HL[(w >> 6) * 66 + (w & 63)] = hv[i];
      }
    }
    __syncthreads();

    // ---- 2. MFMA over K=512: A from WA (b128), B gathered from HL ----
    f32x4 acc = {0.f, 0.f, 0.f, 0.f};
    #pragma unroll
    for (int ks = 0; ks < 16; ++ks) {
      short8v av = *(const short8v*)(waBase + ks * 256);  // ds_read_b128
      union { uint32_t u[4]; short8v v; } bf;
      #pragma unroll
      for (int m = 0; m < 4; ++m)
        bf.u[m] = HL[(ks * 16 + lq * 4 + m) * 66 + hlCol];
      acc = __builtin_amdgcn_mfma_f32_16x16x32_bf16(av, bf.v, acc, 0, 0, 0);
    }

    // ---- add pre-gates, write to gsum (2-way-max banks) ----
    {
      const int colw = bt * 16 + l15;
      #pragma unroll
      for (int r = 0; r < 4; ++r) {
        int row = rt * 16 + lq * 4 + r;
        gsum[GIDX(row, colw)] = acc[r] + pg[r];
      }
    }
    __syncthreads();

    // ---- 3. elementwise: 2 cells (units u0+2p, u0+2p+1) x batch eb ----
    if (tid < 256) {
      const int ul0 = 2 * p, ul1 = 2 * p + 1;
      float gi0 = gsum[GIDX( 0 + ul0, eb)];
      float gf0 = gsum[GIDX( 8 + ul0, eb)];
      float gg0 = gsum[GIDX(16 + ul0, eb)];
      float go0 = gsum[GIDX(24 + ul0, eb)];
      float gi1 = gsum[GIDX( 0 + ul1, eb)];
      float gf1 = gsum[GIDX( 8 + ul1, eb)];
      float gg1 = gsum[GIDX(16 + ul1, eb)];
      float go1 = gsum[GIDX(24 + ul1, eb)];
      float si0 = 1.f / (1.f + __expf(-gi0));
      float sf0 = 1.f / (1.f + __expf(-gf0));
      float so0 = 1.f / (1.f + __expf(-go0));
      float si1 = 1.f / (1.f + __expf(-gi1));
      float sf1 = 1.f / (1.f + __expf(-gf1));
      float so1 = 1.f / (1.f + __expf(-go1));
      c0 = sf0 * c0 + si0 * tanhf(gg0);
      c1 = sf1 * c1 + si1 * tanhf(gg1);
      float h0 = so0 * tanhf(c0);
      float h1 = so1 * tanhf(c1);
      h0l = h0; h1l = h1;
      // COALESCED unit-major store: hb[(g*4+p)*64 + eb], lanes contiguous
      store_coh_u32(&hb[(size_t)((t + 1) & 1) * HB_STRIDE + (size_t)(g * 4 + p) * 64 + eb],
                    bf16r(h0) | (bf16r(h1) << 16));
      float out0 = h0, out1 = h1;
      if (u0 < HHALF) { m0 = fmaxf(m0, h0); m1 = fmaxf(m1, h1); out0 = m0; out1 = m1; }
      PG[((size_t)t * R4H + u0 + 2 * p) * BB + eb]     = out0;  // stash
      PG[((size_t)t * R4H + u0 + 2 * p + 1) * BB + eb] = out1;
    }

    // ---- 4. barrier: release = vmcnt(0); hierarchical monotonic (R6) ----
    asm volatile("s_waitcnt vmcnt(0)" ::: "memory");
    __syncthreads();
    // pg prefetch for t+1 hides under the barrier
    if (t + 1 < TT) {
      #pragma unroll
      for (int r = 0; r < 4; ++r) {
        int lr = rt * 16 + lq * 4 + r;
        pg[r] = PG[((size_t)(t + 1) * R4H + (lr >> 3) * HS + u0 + (lr & 7)) * BB + bt * 16 + l15];
      }
    }
    if (tid == 0) {
      unsigned a = __hip_atomic_fetch_add(grpcnt, 1u, __ATOMIC_RELAXED,
                                          __HIP_MEMORY_SCOPE_AGENT);
      if (a == 8u * (unsigned)(t + 1) - 1u) {
        unsigned b2 = __hip_atomic_fetch_add(cnt2, 1u, __ATOMIC_RELAXED,
                                             __HIP_MEMORY_SCOPE_AGENT);
        if (b2 == 8u * (unsigned)(t + 1) - 1u)
          (void)__hip_atomic_exchange(gen, (unsigned)(t + 1), __ATOMIC_RELAXED,
                                      __HIP_MEMORY_SCOPE_AGENT);
      }
      // failsafe cap: fast wrong-answer instead of a hang; expected wait ~us.
      int spins = 0;
      while (__hip_atomic_load(gen, __ATOMIC_RELAXED,
                               __HIP_MEMORY_SCOPE_AGENT) < (unsigned)(t + 1)) {
        __builtin_amdgcn_s_sleep(1);
        if (++spins > (1 << 16)) break;
      }
    }
    __syncthreads();
  }

  // ---- finals ----
  if (tid < 256) {
    outmem[(size_t)eb * 1280 + 256 + u0 + 2 * p]     = h0l;
    outmem[(size_t)eb * 1280 + 256 + u0 + 2 * p + 1] = h1l;
    outmem[(size_t)eb * 1280 + 768 + u0 + 2 * p]     = c0;
    outmem[(size_t)eb * 1280 + 768 + u0 + 2 * p + 1] = c1;
    if (u0 < HHALF) {
      outmem[(size_t)eb * 1280 + u0 + 2 * p]     = m0;
      outmem[(size_t)eb * 1280 + u0 + 2 * p + 1] = m1;
    }
  }
}

// ---------------------------------------------------------------------------
// Phase 3: out[b][t][u] = PG[t][u][b]  (u < 512)
// ---------------------------------------------------------------------------
__global__ __launch_bounds__(256) void transpose_out(
    const float* __restrict__ PG, float* __restrict__ out)
{
  __shared__ __align__(16) float tileS[64][68];
  const int t = blockIdx.x;
  const int u0 = blockIdx.y * 64;
  const int tid = threadIdx.x;

  {
    int cg = tid & 15, rg = tid >> 4;
    const float* src = PG + (size_t)t * R4H * BB + (size_t)u0 * BB;
    #pragma unroll
    for (int i = 0; i < 4; ++i) {
      int u = rg * 4 + i;
      float4 v = *(const float4*)(src + (size_t)u * BB + cg * 4);
      *(float4*)&tileS[u][cg * 4] = v;
    }
  }
  __syncthreads();
  {
    int ug = tid & 15, bg = tid >> 4;
    #pragma unroll
    for (int i = 0; i < 4; ++i) {
      int b = bg * 4 + i;
      float4 o;
      o.x = tileS[ug * 4 + 0][b];
      o.y = tileS[ug * 4 + 1][b];
      o.z = tileS[ug * 4 + 2][b];
      o.w = tileS[ug * 4 + 3][b];
      *(float4*)&out[((size_t)b * TT + t) * HS + u0 + ug * 4] = o;
    }
  }
}

// ---------------------------------------------------------------------------
extern "C" void kernel_launch(void* const* d_in, const int* in_sizes, int n_in,
                              void* d_out, int out_size, void* d_ws, size_t ws_size,
                              hipStream_t stream)
{
  const float* X   = (const float*)d_in[0];
  const float* mem = (const float*)d_in[1];
  const float* Wih = (const float*)d_in[2];
  const float* Whh = (const float*)d_in[3];
  const float* bih = (const float*)d_in[4];
  const float* bhh = (const float*)d_in[5];

  float* out = (float*)d_out;
  float* outmem = out + (size_t)BB * TT * HS;

  float* PG     = (float*)d_ws;                      // 512*2048*64 f32 = 256 MB
  uint32_t* hbp = (uint32_t*)(PG + (size_t)TT * R4H * BB);  // 2*16384 u32
  unsigned* bar = (unsigned*)(hbp + 2 * HB_STRIDE);  // 2048 u32

  const int dyn_lds = 108544;  // WA 32768 + HL 67584 + gsum 8192
  (void)hipFuncSetAttribute((const void*)lstm_persistent,
                            hipFuncAttributeMaxDynamicSharedMemorySize, dyn_lds);

  hipMemsetAsync(bar, 0, 2048 * sizeof(unsigned), stream);
  init_h<<<dim3(HB_STRIDE / 256), dim3(256), 0, stream>>>(mem, hbp);
  pregemm<<<dim3(TT, 32), dim3(256), 0, stream>>>(X, Wih, bih, bhh, PG);
  lstm_persistent<<<dim3(64), dim3(512), dyn_lds, stream>>>(mem, Whh, PG, hbp, outmem, bar);
  transpose_out<<<dim3(TT, 8), dim3(256), 0, stream>>>(PG, out);
}

// Round 23
// 2679.421 us; speedup vs baseline: 1.1701x; 1.1701x over previous
//
#include <hip/hip_runtime.h>
#include <stdint.h>

#define TT 512
#define BB 64
#define II 256
#define HS 512          // H
#define HHALF 256       // HH
#define R4H 2048        // 4*H
#define HB_STRIDE 16384 // 256 unit-pair rows x 64 batches per h buffer

typedef __attribute__((ext_vector_type(8))) short short8v;  // 8 bf16 = 4 VGPR
typedef __attribute__((ext_vector_type(4))) float f32x4;

// ---------------------------------------------------------------------------
__device__ __forceinline__ uint32_t bf16r(float f) {
  uint32_t u = __float_as_uint(f);
  u += 0x7fffu + ((u >> 16) & 1u);
  return u >> 16;
}

// init (unit-major): hb[0][uh*64 + b] = pack(bf16(h[2uh]), bf16(h[2uh+1]))
__global__ void init_h(const float* __restrict__ mem, uint32_t* __restrict__ hb)
{
  int idx = blockIdx.x * 256 + threadIdx.x;
  if (idx < HB_STRIDE) {
    int uh = idx >> 6, b = idx & 63;
    float lo = mem[(size_t)b * 1280 + 256 + 2 * uh];
    float hi = mem[(size_t)b * 1280 + 256 + 2 * uh + 1];
    hb[idx] = bf16r(lo) | (bf16r(hi) << 16);
  }
}

// ---------------------------------------------------------------------------
// Agent-scope coherent ops (proven R6/R18): relaxed EXCHANGE stores (RMW at
// the IF coherence point; vmcnt(0) ack => globally visible) + relaxed loads
// (bypass stale L1/L2). Must be COALESCED (R12-R17 lesson; R18 proved it).
// ---------------------------------------------------------------------------
__device__ __forceinline__ void store_coh_u32(uint32_t* p, uint32_t v) {
  (void)__hip_atomic_exchange(p, v, __ATOMIC_RELAXED, __HIP_MEMORY_SCOPE_AGENT);
}
__device__ __forceinline__ uint32_t load_coh_u32(const uint32_t* p) {
  return __hip_atomic_load(p, __ATOMIC_RELAXED, __HIP_MEMORY_SCOPE_AGENT);
}
__device__ __forceinline__ void store_coh_f32(float* p, float v) {
  store_coh_u32((uint32_t*)p, __float_as_uint(v));
}
__device__ __forceinline__ float load_coh_f32(const float* p) {
  return __uint_as_float(load_coh_u32((const uint32_t*)p));
}

// gsum addressing: 2-way-max bank pattern via XOR of bit4 with (row>>2)&1
#define GIDX(row, col) (((row) << 6) + ((col) ^ ((((row) >> 2) & 1) << 4)))

// ---------------------------------------------------------------------------
// FUSED persistent kernel (R23). grid = 256 WGs x 512 threads, 1 WG/CU.
//  WGs 0-63  : R18 lstm EXACTLY (single-counter barrier - R22 showed the
//              hierarchical variant is WORSE: serial depth 3 IF RTTs vs 2).
//  WGs 64-255: helpers. Phase A: compute PG (pre-gate GEMM) t-ordered,
//              coalesced sc1 stores, bump pgdone[t] (+2 per 2-tile WG pass).
//              Phase B: poll lstm's gen; transpose finished steps to out.
// lstm gates its PG reads on pgdone[t] (>=32 tiles); helpers' transpose
// gates on gen >= t+1 (published with release-drain by the lstm barrier).
// PG cross-XCD traffic is sc1 both sides. All counters monotonic, memset
// per launch (graph-replay safe).
// ---------------------------------------------------------------------------
__global__ __launch_bounds__(512) void fused_lstm(
    const float* __restrict__ mem,   // [B][1280]
    const float* __restrict__ Whh,   // [4H][H] f32
    const float* __restrict__ X,     // [B][T][I]
    const float* __restrict__ Wih,   // [4H][I]
    const float* __restrict__ bih,
    const float* __restrict__ bhh,
    float* __restrict__ PG,          // [T][4H][B]
    uint32_t* __restrict__ hb,       // [2][256][64] packed bf16x2, unit-major
    float* __restrict__ out,         // [B][T][H]
    float* __restrict__ outmem,      // [B][1280]
    unsigned* __restrict__ bar)      // cnt@0, gen@64, pgdone[512]@128
{
  extern __shared__ uint32_t smem[];
  const int g   = blockIdx.x;
  const int tid = threadIdx.x;
  unsigned* cnt    = bar;
  unsigned* gen    = bar + 64;
  unsigned* pgdone = bar + 128;

  if (g < 64) {
    // ==================== LSTM role (R18 body) ====================
    uint32_t* WA = smem;                 // [2048 slots][4] u32 = 32 KB
    uint32_t* HL = smem + 8192;          // [256][66] u32
    float*  gsum = (float*)(smem + 8192 + 16896);  // [32*64] f32

    const int wu   = tid >> 6;
    const int lane = tid & 63;
    const int l15  = lane & 15;
    const int lq   = lane >> 4;
    const int bt   = wu & 3;
    const int rt   = wu >> 2;
    const int u0   = g * 8;

    // ---- stage W slice into LDS in A-fragment order (once) ----
    #pragma unroll
    for (int s = 0; s < 4; ++s) {
      int slot = s * 512 + tid;
      int srt  = slot >> 10;
      int rem  = slot & 1023;
      int sks  = rem >> 6;
      int ln   = rem & 63;
      int sl15 = ln & 15, slq = ln >> 4;
      int lr   = srt * 16 + sl15;
      int grow = (lr >> 3) * HS + u0 + (lr & 7);
      const float* wp = Whh + (size_t)grow * HS + slq * 8 + sks * 32;
      float4 x0 = *(const float4*)(wp);
      float4 x1 = *(const float4*)(wp + 4);
      uint32_t* dst = WA + (size_t)slot * 4;
      dst[0] = bf16r(x0.x) | (bf16r(x0.y) << 16);
      dst[1] = bf16r(x0.z) | (bf16r(x0.w) << 16);
      dst[2] = bf16r(x1.x) | (bf16r(x1.y) << 16);
      dst[3] = bf16r(x1.z) | (bf16r(x1.w) << 16);
    }

    const int p = tid >> 6;            // unit-pair 0..3 (valid tid<256)
    const int eb = lane;
    float c0 = 0.f, c1 = 0.f, m0 = 0.f, m1 = 0.f, h0l = 0.f, h1l = 0.f;
    if (tid < 256) {
      c0 = mem[(size_t)eb * 1280 + 768 + u0 + 2 * p];
      c1 = mem[(size_t)eb * 1280 + 768 + u0 + 2 * p + 1];
      if (u0 < HHALF) {
        m0 = mem[(size_t)eb * 1280 + u0 + 2 * p];
        m1 = mem[(size_t)eb * 1280 + u0 + 2 * p + 1];
      }
    }

    // wait until helpers produced PG[0]
    if (tid == 0) {
      int spins = 0;
      while (__hip_atomic_load(pgdone, __ATOMIC_RELAXED,
                               __HIP_MEMORY_SCOPE_AGENT) < 32u) {
        __builtin_amdgcn_s_sleep(2);
        if (++spins > (1 << 17)) break;
      }
    }
    __syncthreads();  // W staged + PG[0] ready

    const uint32_t* waBase = WA + ((size_t)(rt * 16) * 64 + lane) * 4;
    const int hlCol = bt * 16 + l15;

    for (int t = 0; t < TT; ++t) {
      // ---- pg prefetch for THIS step (safe: a WG's gate-i rows == its own
      //      stash rows; ordered by program order + intra-step syncs) ----
      float pg[4];
      #pragma unroll
      for (int r = 0; r < 4; ++r) {
        int lr = rt * 16 + lq * 4 + r;
        pg[r] = load_coh_f32(&PG[((size_t)t * R4H + (lr >> 3) * HS + u0 + (lr & 7)) * BB + bt * 16 + l15]);
      }

      // ---- 1. stage h: coalesced sc1 loads -> conflict-free LDS ----
      {
        const uint32_t* hcur = hb + (size_t)(t & 1) * HB_STRIDE;
        uint32_t hv[32];
        #pragma unroll
        for (int i = 0; i < 32; ++i) hv[i] = load_coh_u32(hcur + tid + i * 512);
        #pragma unroll
        for (int i = 0; i < 32; ++i) {
          int w = tid + i * 512;
          HL[(w >> 6) * 66 + (w & 63)] = hv[i];
        }
      }
      __syncthreads();

      // ---- 2. MFMA over K=512 ----
      f32x4 acc = {0.f, 0.f, 0.f, 0.f};
      #pragma unroll
      for (int ks = 0; ks < 16; ++ks) {
        short8v av = *(const short8v*)(waBase + ks * 256);
        union { uint32_t u[4]; short8v v; } bf;
        #pragma unroll
        for (int m = 0; m < 4; ++m)
          bf.u[m] = HL[(ks * 16 + lq * 4 + m) * 66 + hlCol];
        acc = __builtin_amdgcn_mfma_f32_16x16x32_bf16(av, bf.v, acc, 0, 0, 0);
      }

      // ---- gsum (+pre-gates) ----
      {
        const int colw = bt * 16 + l15;
        #pragma unroll
        for (int r = 0; r < 4; ++r) {
          int row = rt * 16 + lq * 4 + r;
          gsum[GIDX(row, colw)] = acc[r] + pg[r];
        }
      }
      __syncthreads();

      // ---- 3. elementwise (tid<256) ----
      if (tid < 256) {
        const int ul0 = 2 * p, ul1 = 2 * p + 1;
        float gi0 = gsum[GIDX( 0 + ul0, eb)];
        float gf0 = gsum[GIDX( 8 + ul0, eb)];
        float gg0 = gsum[GIDX(16 + ul0, eb)];
        float go0 = gsum[GIDX(24 + ul0, eb)];
        float gi1 = gsum[GIDX( 0 + ul1, eb)];
        float gf1 = gsum[GIDX( 8 + ul1, eb)];
        float gg1 = gsum[GIDX(16 + ul1, eb)];
        float go1 = gsum[GIDX(24 + ul1, eb)];
        float si0 = 1.f / (1.f + __expf(-gi0));
        float sf0 = 1.f / (1.f + __expf(-gf0));
        float so0 = 1.f / (1.f + __expf(-go0));
        float si1 = 1.f / (1.f + __expf(-gi1));
        float sf1 = 1.f / (1.f + __expf(-gf1));
        float so1 = 1.f / (1.f + __expf(-go1));
        c0 = sf0 * c0 + si0 * tanhf(gg0);
        c1 = sf1 * c1 + si1 * tanhf(gg1);
        float h0 = so0 * tanhf(c0);
        float h1 = so1 * tanhf(c1);
        h0l = h0; h1l = h1;
        store_coh_u32(&hb[(size_t)((t + 1) & 1) * HB_STRIDE + (size_t)(g * 4 + p) * 64 + eb],
                      bf16r(h0) | (bf16r(h1) << 16));
        float out0 = h0, out1 = h1;
        if (u0 < HHALF) { m0 = fmaxf(m0, h0); m1 = fmaxf(m1, h1); out0 = m0; out1 = m1; }
        // stash (sc1: read by helper transpose WGs on other XCDs)
        store_coh_f32(&PG[((size_t)t * R4H + u0 + 2 * p) * BB + eb], out0);
        store_coh_f32(&PG[((size_t)t * R4H + u0 + 2 * p + 1) * BB + eb], out1);
      }

      // ---- 4. barrier: release = vmcnt(0); single monotonic counter ----
      asm volatile("s_waitcnt vmcnt(0)" ::: "memory");
      __syncthreads();
      if (tid == 0) {
        unsigned a = __hip_atomic_fetch_add(cnt, 1u, __ATOMIC_RELAXED,
                                            __HIP_MEMORY_SCOPE_AGENT);
        if (a == 64u * (unsigned)(t + 1) - 1u)
          (void)__hip_atomic_exchange(gen, (unsigned)(t + 1), __ATOMIC_RELAXED,
                                      __HIP_MEMORY_SCOPE_AGENT);
        int spins = 0;
        while (__hip_atomic_load(gen, __ATOMIC_RELAXED,
                                 __HIP_MEMORY_SCOPE_AGENT) < (unsigned)(t + 1)) {
          __builtin_amdgcn_s_sleep(1);
          if (++spins > (1 << 16)) break;
        }
        if (t + 1 < TT) {   // gate next step's pg prefetch
          spins = 0;
          while (__hip_atomic_load(pgdone + t + 1, __ATOMIC_RELAXED,
                                   __HIP_MEMORY_SCOPE_AGENT) < 32u) {
            __builtin_amdgcn_s_sleep(1);
            if (++spins > (1 << 16)) break;
          }
        }
      }
      __syncthreads();
    }

    if (tid < 256) {
      outmem[(size_t)eb * 1280 + 256 + u0 + 2 * p]     = h0l;
      outmem[(size_t)eb * 1280 + 256 + u0 + 2 * p + 1] = h1l;
      outmem[(size_t)eb * 1280 + 768 + u0 + 2 * p]     = c0;
      outmem[(size_t)eb * 1280 + 768 + u0 + 2 * p + 1] = c1;
      if (u0 < HHALF) {
        outmem[(size_t)eb * 1280 + u0 + 2 * p]     = m0;
        outmem[(size_t)eb * 1280 + u0 + 2 * p + 1] = m1;
      }
    }
  } else {
    // ==================== helper role ====================
    const int hh = g - 64;             // 0..191
    float* XsH  = (float*)smem;        // [64][68]
    float* Ws0H = XsH + 64 * 68;
    float* Ws1H = Ws0H + 64 * 68;
    float* LOut = Ws1H + 64 * 68;      // [2][64*66]
    uint32_t* TR = smem;               // transpose reuse [64*66]

    const int hf = tid >> 8;           // 0/1 (tile half)
    const int t256 = tid & 255;
    const int cg = t256 & 15, rg = t256 >> 4;

    // ---- Phase A: pre-gate GEMM, t-major tile-pairs ----
    for (int tp = hh; tp < 8192; tp += 192) {
      const int t = tp >> 4, rp = tp & 15;
      float acc[4][4] = {};
      for (int k0 = 0; k0 < II; k0 += 64) {
        __syncthreads();   // protect staging from previous chunk's readers
        #pragma unroll
        for (int ps = 0; ps < 6; ++ps) {
          int slot = ps * 512 + tid;   // 0..3071
          int arr = slot >> 10;        // 0:Xs 1:Ws0 2:Ws1
          int idx = slot & 1023;
          int r = idx >> 4, q = idx & 15;
          const float* src;
          float* dst;
          if (arr == 0) { src = X + ((size_t)r * TT + t) * II + k0 + q * 4; dst = XsH; }
          else {
            int rb = (rp * 2 + arr - 1) * 64;
            src = Wih + (size_t)(rb + r) * II + k0 + q * 4;
            dst = (arr == 1) ? Ws0H : Ws1H;
          }
          float4 v = *(const float4*)src;
          dst[(q * 4 + 0) * 68 + r] = v.x;
          dst[(q * 4 + 1) * 68 + r] = v.y;
          dst[(q * 4 + 2) * 68 + r] = v.z;
          dst[(q * 4 + 3) * 68 + r] = v.w;
        }
        __syncthreads();
        const float* WsH = hf ? Ws1H : Ws0H;
        #pragma unroll 8
        for (int kk = 0; kk < 64; ++kk) {
          float4 a = *(const float4*)&WsH[kk * 68 + rg * 4];
          float4 x = *(const float4*)&XsH[kk * 68 + cg * 4];
          float av[4] = {a.x, a.y, a.z, a.w};
          float xv[4] = {x.x, x.y, x.z, x.w};
          #pragma unroll
          for (int i = 0; i < 4; ++i)
            #pragma unroll
            for (int j = 0; j < 4; ++j)
              acc[i][j] = fmaf(av[i], xv[j], acc[i][j]);
        }
      }
      // bias + staging for linear store
      {
        int rbH = (rp * 2 + hf) * 64;
        #pragma unroll
        for (int i = 0; i < 4; ++i) {
          int row = rg * 4 + i;
          float bias = bih[rbH + row] + bhh[rbH + row];
          #pragma unroll
          for (int j = 0; j < 4; ++j)
            LOut[hf * 4224 + row * 66 + cg * 4 + j] = acc[i][j] + bias;
        }
      }
      __syncthreads();
      // coalesced sc1 stores (256B/wave-instruction)
      {
        uint32_t* pgU = (uint32_t*)PG + ((size_t)t * R4H + (rp * 2 + hf) * 64) * BB;
        #pragma unroll
        for (int j = 0; j < 16; ++j) {
          int e = j * 256 + t256;
          store_coh_u32(pgU + e,
                        __float_as_uint(LOut[hf * 4224 + (e >> 6) * 66 + (e & 63)]));
        }
      }
      asm volatile("s_waitcnt vmcnt(0)" ::: "memory");
      __syncthreads();
      if (tid == 0)
        (void)__hip_atomic_fetch_add(pgdone + t, 2u, __ATOMIC_RELAXED,
                                     __HIP_MEMORY_SCOPE_AGENT);
    }

    // ---- Phase B: transpose finished steps (poll lstm's gen) ----
    for (int ti = hh; ti < 4096; ti += 192) {
      const int t = ti >> 3, ut = ti & 7;
      if (tid == 0) {
        int spins = 0;
        while (__hip_atomic_load(gen, __ATOMIC_RELAXED,
                                 __HIP_MEMORY_SCOPE_AGENT) < (unsigned)(t + 1)) {
          __builtin_amdgcn_s_sleep(2);
          if (++spins > (1 << 17)) break;
        }
      }
      __syncthreads();
      const uint32_t* srcU = (const uint32_t*)PG + ((size_t)t * R4H + ut * 64) * BB;
      #pragma unroll
      for (int j = 0; j < 8; ++j) {
        int e = j * 512 + tid;
        TR[(e >> 6) * 66 + (e & 63)] = load_coh_u32(srcU + e);
      }
      __syncthreads();
      {
        int w = tid >> 6, lane = tid & 63;
        #pragma unroll
        for (int bb = 0; bb < 8; ++bb) {
          int b = w * 8 + bb;
          out[((size_t)b * TT + t) * HS + ut * 64 + lane] =
              __uint_as_float(TR[lane * 66 + b]);
        }
      }
      __syncthreads();
    }
  }
}

// ---------------------------------------------------------------------------
extern "C" void kernel_launch(void* const* d_in, const int* in_sizes, int n_in,
                              void* d_out, int out_size, void* d_ws, size_t ws_size,
                              hipStream_t stream)
{
  const float* X   = (const float*)d_in[0];
  const float* mem = (const float*)d_in[1];
  const float* Wih = (const float*)d_in[2];
  const float* Whh = (const float*)d_in[3];
  const float* bih = (const float*)d_in[4];
  const float* bhh = (const float*)d_in[5];

  float* out = (float*)d_out;
  float* outmem = out + (size_t)BB * TT * HS;

  float* PG     = (float*)d_ws;                      // 512*2048*64 f32 = 256 MB
  uint32_t* hbp = (uint32_t*)(PG + (size_t)TT * R4H * BB);  // 2*16384 u32
  unsigned* bar = (unsigned*)(hbp + 2 * HB_STRIDE);  // 2048 u32 (incl pgdone)

  const int dyn_lds = 108544;  // max(lstm: 32K+66K+8K, helper: 86K)
  (void)hipFuncSetAttribute((const void*)fused_lstm,
                            hipFuncAttributeMaxDynamicSharedMemorySize, dyn_lds);

  hipMemsetAsync(bar, 0, 2048 * sizeof(unsigned), stream);
  init_h<<<dim3(HB_STRIDE / 256), dim3(256), 0, stream>>>(mem, hbp);
  fused_lstm<<<dim3(256), dim3(512), dyn_lds, stream>>>(
      mem, Whh, X, Wih, bih, bhh, PG, hbp, out, outmem, bar);
}

// Round 24
// 2433.983 us; speedup vs baseline: 1.2881x; 1.1008x over previous
//
#include <hip/hip_runtime.h>
#include <stdint.h>

#define TT 512
#define BB 64
#define II 256
#define HS 512          // H
#define HHALF 256       // HH
#define R4H 2048        // 4*H
#define HB_STRIDE 16384 // 256 unit-pair rows x 64 batches per h buffer

typedef __attribute__((ext_vector_type(8))) short short8v;  // 8 bf16 = 4 VGPR
typedef __attribute__((ext_vector_type(4))) float f32x4;

// ---------------------------------------------------------------------------
__device__ __forceinline__ uint32_t bf16r(float f) {
  uint32_t u = __float_as_uint(f);
  u += 0x7fffu + ((u >> 16) & 1u);
  return u >> 16;
}

// init (unit-major): hb[0][uh*64 + b] = pack(bf16(h[2uh]), bf16(h[2uh+1]))
__global__ void init_h(const float* __restrict__ mem, uint32_t* __restrict__ hb)
{
  int idx = blockIdx.x * 256 + threadIdx.x;
  if (idx < HB_STRIDE) {
    int uh = idx >> 6, b = idx & 63;
    float lo = mem[(size_t)b * 1280 + 256 + 2 * uh];
    float hi = mem[(size_t)b * 1280 + 256 + 2 * uh + 1];
    hb[idx] = bf16r(lo) | (bf16r(hi) << 16);
  }
}

// ---------------------------------------------------------------------------
// Agent-scope coherent ops (proven R6/R18): relaxed EXCHANGE stores (RMW at
// the IF coherence point; vmcnt(0) ack => globally visible) + relaxed loads
// (bypass stale L1/L2). Must be COALESCED (R12-R17 lesson; R18 proved it).
// ---------------------------------------------------------------------------
__device__ __forceinline__ void store_coh_u32(uint32_t* p, uint32_t v) {
  (void)__hip_atomic_exchange(p, v, __ATOMIC_RELAXED, __HIP_MEMORY_SCOPE_AGENT);
}
__device__ __forceinline__ uint32_t load_coh_u32(const uint32_t* p) {
  return __hip_atomic_load(p, __ATOMIC_RELAXED, __HIP_MEMORY_SCOPE_AGENT);
}
__device__ __forceinline__ void store_coh_f32(float* p, float v) {
  store_coh_u32((uint32_t*)p, __float_as_uint(v));
}
__device__ __forceinline__ float load_coh_f32(const float* p) {
  return __uint_as_float(load_coh_u32((const uint32_t*)p));
}

// gsum addressing: 2-way-max bank pattern via XOR of bit4 with (row>>2)&1
#define GIDX(row, col) (((row) << 6) + ((col) ^ ((((row) >> 2) & 1) << 4)))

// ---------------------------------------------------------------------------
// FUSED persistent kernel (R24). grid = 256 WGs x 512 threads, 1 WG/CU.
//  WGs 0-63  : lstm (R18 body). R24 barrier: DISTRIBUTED FLAGS. Each WG is
//    the single writer of its h rows, so no central counter: after the
//    vmcnt(0) drain, WG g fire-and-forgets flag[g]=t+1 (own 256B line).
//    Readers: wave-0 lane l polls flag[l] -- 64 parallel loads + __all()
//    per iteration => ~1 IF RTT discovery vs R23's RMW-ack -> exchange ->
//    poll (~2.5 RTT serial). Induction safety: flag[w]>=t+1 => WG w has
//    finished LOADING h[t], so buffer (t+1)&1 is safe to overwrite at t+2.
//  WGs 64-255: helpers. Phase A: pre-gate GEMM t-ordered, coalesced sc1
//    stores, bump pgdone[t]. Phase B: poll flags; transpose finished steps.
// bar layout: flags[64]@(128 + w*64), pgdone[512]@4224. memset per launch.
// ---------------------------------------------------------------------------
__global__ __launch_bounds__(512) void fused_lstm(
    const float* __restrict__ mem,   // [B][1280]
    const float* __restrict__ Whh,   // [4H][H] f32
    const float* __restrict__ X,     // [B][T][I]
    const float* __restrict__ Wih,   // [4H][I]
    const float* __restrict__ bih,
    const float* __restrict__ bhh,
    float* __restrict__ PG,          // [T][4H][B]
    uint32_t* __restrict__ hb,       // [2][256][64] packed bf16x2, unit-major
    float* __restrict__ out,         // [B][T][H]
    float* __restrict__ outmem,      // [B][1280]
    unsigned* __restrict__ bar)
{
  extern __shared__ uint32_t smem[];
  const int g   = blockIdx.x;
  const int tid = threadIdx.x;
  unsigned* flags  = bar + 128;      // flag[w] at flags[w*64]
  unsigned* pgdone = bar + 4224;

  if (g < 64) {
    // ==================== LSTM role ====================
    uint32_t* WA = smem;                 // [2048 slots][4] u32 = 32 KB
    uint32_t* HL = smem + 8192;          // [256][66] u32
    float*  gsum = (float*)(smem + 8192 + 16896);  // [32*64] f32

    const int wu   = tid >> 6;
    const int lane = tid & 63;
    const int l15  = lane & 15;
    const int lq   = lane >> 4;
    const int bt   = wu & 3;
    const int rt   = wu >> 2;
    const int u0   = g * 8;

    // ---- stage W slice into LDS in A-fragment order (once) ----
    #pragma unroll
    for (int s = 0; s < 4; ++s) {
      int slot = s * 512 + tid;
      int srt  = slot >> 10;
      int rem  = slot & 1023;
      int sks  = rem >> 6;
      int ln   = rem & 63;
      int sl15 = ln & 15, slq = ln >> 4;
      int lr   = srt * 16 + sl15;
      int grow = (lr >> 3) * HS + u0 + (lr & 7);
      const float* wp = Whh + (size_t)grow * HS + slq * 8 + sks * 32;
      float4 x0 = *(const float4*)(wp);
      float4 x1 = *(const float4*)(wp + 4);
      uint32_t* dst = WA + (size_t)slot * 4;
      dst[0] = bf16r(x0.x) | (bf16r(x0.y) << 16);
      dst[1] = bf16r(x0.z) | (bf16r(x0.w) << 16);
      dst[2] = bf16r(x1.x) | (bf16r(x1.y) << 16);
      dst[3] = bf16r(x1.z) | (bf16r(x1.w) << 16);
    }

    const int p = tid >> 6;            // unit-pair 0..3 (valid tid<256)
    const int eb = lane;
    float c0 = 0.f, c1 = 0.f, m0 = 0.f, m1 = 0.f, h0l = 0.f, h1l = 0.f;
    if (tid < 256) {
      c0 = mem[(size_t)eb * 1280 + 768 + u0 + 2 * p];
      c1 = mem[(size_t)eb * 1280 + 768 + u0 + 2 * p + 1];
      if (u0 < HHALF) {
        m0 = mem[(size_t)eb * 1280 + u0 + 2 * p];
        m1 = mem[(size_t)eb * 1280 + u0 + 2 * p + 1];
      }
    }

    // wait until helpers produced PG[0]
    if (tid == 0) {
      int spins = 0;
      while (__hip_atomic_load(pgdone, __ATOMIC_RELAXED,
                               __HIP_MEMORY_SCOPE_AGENT) < 32u) {
        __builtin_amdgcn_s_sleep(2);
        if (++spins > (1 << 17)) break;
      }
    }
    __syncthreads();  // W staged + PG[0] ready

    const uint32_t* waBase = WA + ((size_t)(rt * 16) * 64 + lane) * 4;
    const int hlCol = bt * 16 + l15;

    for (int t = 0; t < TT; ++t) {
      // ---- pg prefetch for THIS step ----
      float pg[4];
      #pragma unroll
      for (int r = 0; r < 4; ++r) {
        int lr = rt * 16 + lq * 4 + r;
        pg[r] = load_coh_f32(&PG[((size_t)t * R4H + (lr >> 3) * HS + u0 + (lr & 7)) * BB + bt * 16 + l15]);
      }

      // ---- 1. stage h: coalesced sc1 loads -> conflict-free LDS ----
      {
        const uint32_t* hcur = hb + (size_t)(t & 1) * HB_STRIDE;
        uint32_t hv[32];
        #pragma unroll
        for (int i = 0; i < 32; ++i) hv[i] = load_coh_u32(hcur + tid + i * 512);
        #pragma unroll
        for (int i = 0; i < 32; ++i) {
          int w = tid + i * 512;
          HL[(w >> 6) * 66 + (w & 63)] = hv[i];
        }
      }
      __syncthreads();

      // ---- 2. MFMA over K=512 ----
      f32x4 acc = {0.f, 0.f, 0.f, 0.f};
      #pragma unroll
      for (int ks = 0; ks < 16; ++ks) {
        short8v av = *(const short8v*)(waBase + ks * 256);
        union { uint32_t u[4]; short8v v; } bf;
        #pragma unroll
        for (int m = 0; m < 4; ++m)
          bf.u[m] = HL[(ks * 16 + lq * 4 + m) * 66 + hlCol];
        acc = __builtin_amdgcn_mfma_f32_16x16x32_bf16(av, bf.v, acc, 0, 0, 0);
      }

      // ---- gsum (+pre-gates) ----
      {
        const int colw = bt * 16 + l15;
        #pragma unroll
        for (int r = 0; r < 4; ++r) {
          int row = rt * 16 + lq * 4 + r;
          gsum[GIDX(row, colw)] = acc[r] + pg[r];
        }
      }
      __syncthreads();

      // ---- 3. elementwise (tid<256) ----
      if (tid < 256) {
        const int ul0 = 2 * p, ul1 = 2 * p + 1;
        float gi0 = gsum[GIDX( 0 + ul0, eb)];
        float gf0 = gsum[GIDX( 8 + ul0, eb)];
        float gg0 = gsum[GIDX(16 + ul0, eb)];
        float go0 = gsum[GIDX(24 + ul0, eb)];
        float gi1 = gsum[GIDX( 0 + ul1, eb)];
        float gf1 = gsum[GIDX( 8 + ul1, eb)];
        float gg1 = gsum[GIDX(16 + ul1, eb)];
        float go1 = gsum[GIDX(24 + ul1, eb)];
        float si0 = 1.f / (1.f + __expf(-gi0));
        float sf0 = 1.f / (1.f + __expf(-gf0));
        float so0 = 1.f / (1.f + __expf(-go0));
        float si1 = 1.f / (1.f + __expf(-gi1));
        float sf1 = 1.f / (1.f + __expf(-gf1));
        float so1 = 1.f / (1.f + __expf(-go1));
        c0 = sf0 * c0 + si0 * tanhf(gg0);
        c1 = sf1 * c1 + si1 * tanhf(gg1);
        float h0 = so0 * tanhf(c0);
        float h1 = so1 * tanhf(c1);
        h0l = h0; h1l = h1;
        store_coh_u32(&hb[(size_t)((t + 1) & 1) * HB_STRIDE + (size_t)(g * 4 + p) * 64 + eb],
                      bf16r(h0) | (bf16r(h1) << 16));
        float out0 = h0, out1 = h1;
        if (u0 < HHALF) { m0 = fmaxf(m0, h0); m1 = fmaxf(m1, h1); out0 = m0; out1 = m1; }
        // stash (sc1: read by helper transpose WGs on other XCDs)
        store_coh_f32(&PG[((size_t)t * R4H + u0 + 2 * p) * BB + eb], out0);
        store_coh_f32(&PG[((size_t)t * R4H + u0 + 2 * p + 1) * BB + eb], out1);
      }

      // ---- 4. publish flag after drain; wait for all 64 flags ----
      asm volatile("s_waitcnt vmcnt(0)" ::: "memory");
      __syncthreads();                 // all waves drained their stores
      if (tid == 0)
        store_coh_u32(flags + g * 64, (unsigned)(t + 1));   // fire-and-forget
      if (tid < 64) {
        int spins = 0;
        for (;;) {
          unsigned v = load_coh_u32(flags + tid * 64);
          if (__all(v >= (unsigned)(t + 1))) break;
          __builtin_amdgcn_s_sleep(1);
          if (++spins > (1 << 16)) break;   // failsafe: no hang
        }
      }
      if (tid == 0 && t + 1 < TT) {    // gate next step's pg reads
        int spins = 0;
        while (__hip_atomic_load(pgdone + t + 1, __ATOMIC_RELAXED,
                                 __HIP_MEMORY_SCOPE_AGENT) < 32u) {
          __builtin_amdgcn_s_sleep(1);
          if (++spins > (1 << 16)) break;
        }
      }
      __syncthreads();
    }

    if (tid < 256) {
      outmem[(size_t)eb * 1280 + 256 + u0 + 2 * p]     = h0l;
      outmem[(size_t)eb * 1280 + 256 + u0 + 2 * p + 1] = h1l;
      outmem[(size_t)eb * 1280 + 768 + u0 + 2 * p]     = c0;
      outmem[(size_t)eb * 1280 + 768 + u0 + 2 * p + 1] = c1;
      if (u0 < HHALF) {
        outmem[(size_t)eb * 1280 + u0 + 2 * p]     = m0;
        outmem[(size_t)eb * 1280 + u0 + 2 * p + 1] = m1;
      }
    }
  } else {
    // ==================== helper role ====================
    const int hh = g - 64;             // 0..191
    float* XsH  = (float*)smem;        // [64][68]
    float* Ws0H = XsH + 64 * 68;
    float* Ws1H = Ws0H + 64 * 68;
    float* LOut = Ws1H + 64 * 68;      // [2][64*66]
    uint32_t* TR = smem;               // transpose reuse [64*66]

    const int hf = tid >> 8;           // 0/1 (tile half)
    const int t256 = tid & 255;
    const int cg = t256 & 15, rg = t256 >> 4;

    // ---- Phase A: pre-gate GEMM, t-major tile-pairs ----
    for (int tp = hh; tp < 8192; tp += 192) {
      const int t = tp >> 4, rp = tp & 15;
      float acc[4][4] = {};
      for (int k0 = 0; k0 < II; k0 += 64) {
        __syncthreads();   // protect staging from previous chunk's readers
        #pragma unroll
        for (int ps = 0; ps < 6; ++ps) {
          int slot = ps * 512 + tid;   // 0..3071
          int arr = slot >> 10;        // 0:Xs 1:Ws0 2:Ws1
          int idx = slot & 1023;
          int r = idx >> 4, q = idx & 15;
          const float* src;
          float* dst;
          if (arr == 0) { src = X + ((size_t)r * TT + t) * II + k0 + q * 4; dst = XsH; }
          else {
            int rb = (rp * 2 + arr - 1) * 64;
            src = Wih + (size_t)(rb + r) * II + k0 + q * 4;
            dst = (arr == 1) ? Ws0H : Ws1H;
          }
          float4 v = *(const float4*)src;
          dst[(q * 4 + 0) * 68 + r] = v.x;
          dst[(q * 4 + 1) * 68 + r] = v.y;
          dst[(q * 4 + 2) * 68 + r] = v.z;
          dst[(q * 4 + 3) * 68 + r] = v.w;
        }
        __syncthreads();
        const float* WsH = hf ? Ws1H : Ws0H;
        #pragma unroll 8
        for (int kk = 0; kk < 64; ++kk) {
          float4 a = *(const float4*)&WsH[kk * 68 + rg * 4];
          float4 x = *(const float4*)&XsH[kk * 68 + cg * 4];
          float av[4] = {a.x, a.y, a.z, a.w};
          float xv[4] = {x.x, x.y, x.z, x.w};
          #pragma unroll
          for (int i = 0; i < 4; ++i)
            #pragma unroll
            for (int j = 0; j < 4; ++j)
              acc[i][j] = fmaf(av[i], xv[j], acc[i][j]);
        }
      }
      // bias + staging for linear store
      {
        int rbH = (rp * 2 + hf) * 64;
        #pragma unroll
        for (int i = 0; i < 4; ++i) {
          int row = rg * 4 + i;
          float bias = bih[rbH + row] + bhh[rbH + row];
          #pragma unroll
          for (int j = 0; j < 4; ++j)
            LOut[hf * 4224 + row * 66 + cg * 4 + j] = acc[i][j] + bias;
        }
      }
      __syncthreads();
      // coalesced sc1 stores (256B/wave-instruction)
      {
        uint32_t* pgU = (uint32_t*)PG + ((size_t)t * R4H + (rp * 2 + hf) * 64) * BB;
        #pragma unroll
        for (int j = 0; j < 16; ++j) {
          int e = j * 256 + t256;
          store_coh_u32(pgU + e,
                        __float_as_uint(LOut[hf * 4224 + (e >> 6) * 66 + (e & 63)]));
        }
      }
      asm volatile("s_waitcnt vmcnt(0)" ::: "memory");
      __syncthreads();
      if (tid == 0)
        (void)__hip_atomic_fetch_add(pgdone + t, 2u, __ATOMIC_RELAXED,
                                     __HIP_MEMORY_SCOPE_AGENT);
    }

    // ---- Phase B: transpose finished steps (poll lstm flags) ----
    for (int ti = hh; ti < 4096; ti += 192) {
      const int t = ti >> 3, ut = ti & 7;
      if (tid < 64) {
        int spins = 0;
        for (;;) {
          unsigned v = load_coh_u32(flags + tid * 64);
          if (__all(v >= (unsigned)(t + 1))) break;
          __builtin_amdgcn_s_sleep(2);
          if (++spins > (1 << 17)) break;
        }
      }
      __syncthreads();
      const uint32_t* srcU = (const uint32_t*)PG + ((size_t)t * R4H + ut * 64) * BB;
      #pragma unroll
      for (int j = 0; j < 8; ++j) {
        int e = j * 512 + tid;
        TR[(e >> 6) * 66 + (e & 63)] = load_coh_u32(srcU + e);
      }
      __syncthreads();
      {
        int w = tid >> 6, lane = tid & 63;
        #pragma unroll
        for (int bb = 0; bb < 8; ++bb) {
          int b = w * 8 + bb;
          out[((size_t)b * TT + t) * HS + ut * 64 + lane] =
              __uint_as_float(TR[lane * 66 + b]);
        }
      }
      __syncthreads();
    }
  }
}

// ---------------------------------------------------------------------------
extern "C" void kernel_launch(void* const* d_in, const int* in_sizes, int n_in,
                              void* d_out, int out_size, void* d_ws, size_t ws_size,
                              hipStream_t stream)
{
  const float* X   = (const float*)d_in[0];
  const float* mem = (const float*)d_in[1];
  const float* Wih = (const float*)d_in[2];
  const float* Whh = (const float*)d_in[3];
  const float* bih = (const float*)d_in[4];
  const float* bhh = (const float*)d_in[5];

  float* out = (float*)d_out;
  float* outmem = out + (size_t)BB * TT * HS;

  float* PG     = (float*)d_ws;                      // 512*2048*64 f32 = 256 MB
  uint32_t* hbp = (uint32_t*)(PG + (size_t)TT * R4H * BB);  // 2*16384 u32
  unsigned* bar = (unsigned*)(hbp + 2 * HB_STRIDE);  // 8192 u32 (flags+pgdone)

  const int dyn_lds = 108544;  // max(lstm: 32K+66K+8K, helper: 86K)
  (void)hipFuncSetAttribute((const void*)fused_lstm,
                            hipFuncAttributeMaxDynamicSharedMemorySize, dyn_lds);

  hipMemsetAsync(bar, 0, 8192 * sizeof(unsigned), stream);
  init_h<<<dim3(HB_STRIDE / 256), dim3(256), 0, stream>>>(mem, hbp);
  fused_lstm<<<dim3(256), dim3(512), dyn_lds, stream>>>(
      mem, Whh, X, Wih, bih, bhh, PG, hbp, out, outmem, bar);
}